// Round 5
// baseline (141.480 us; speedup 1.0000x reference)
//
#include <hip/hip_runtime.h>

#define B_    4
#define N1_   16384
#define N2_   4096
#define C1_   64
#define C2_   128
#define BQ    64            // queries per block
#define WV_   8             // waves per block
#define CHUNK (N2_ / WV_)   // candidates per wave in phase 1 = 512

typedef __attribute__((ext_vector_type(8))) short bf16x8;
typedef __attribute__((ext_vector_type(4))) float f32x4;
typedef __attribute__((ext_vector_type(4))) unsigned short u16x4;

__device__ __forceinline__ unsigned short f2bf(float f) {
  unsigned int u = __builtin_bit_cast(unsigned int, f);
  unsigned int r = (u + 0x7FFFu + ((u >> 16) & 1u)) >> 16;
  return (unsigned short)r;
}

// insert (db,jj) into sorted triple (d0,i0)<=(d1,i1)<=(d2,i2), keep 3 smallest.
// 3 v_cmp + 10 cndmask/min/max, all full-rate, no serial vcc chain across streams.
// strict < : incumbent wins ties (scan order = ascending idx -> stable).
#define INS3P(db, jj, d0, i0, d1, i1, d2, i2) do {          \
    const bool _c0 = (db) < (d0);                            \
    const unsigned _ad = _c0 ? (d0) : (db);                  \
    const unsigned _ai = _c0 ? (i0) : (jj);                  \
    (i0) = _c0 ? (jj) : (i0);                                \
    (d0) = _c0 ? (db) : (d0);                                \
    const bool _c1 = _ad < (d1);                             \
    const unsigned _bd = _c1 ? (d1) : _ad;                   \
    const unsigned _bi = _c1 ? (i1) : _ai;                   \
    (i1) = _c1 ? _ai : (i1);                                 \
    (d1) = _c1 ? _ad : (d1);                                 \
    const bool _c2 = _bd < (d2);                             \
    (i2) = _c2 ? _bi : (i2);                                 \
    (d2) = _c2 ? _bd : (d2);                                 \
  } while (0)

// ---- prep: pack candidates (-2x,-2y,-2z,|c|^2), transpose W1/W2 to bf16 ----
__global__ void prep_kernel(const float* __restrict__ xyz2, const float* __restrict__ W1,
                            const float* __restrict__ W2,
                            float4* __restrict__ cand, unsigned short* __restrict__ w1t,
                            unsigned short* __restrict__ w2t) {
  int t = blockIdx.x * 256 + threadIdx.x;
  const int NC  = B_ * N2_;     // 16384
  const int NW1 = 192 * 128;    // 24576
  const int NW2 = 128 * 128;    // 16384
  if (t < NC) {
    float x = xyz2[t * 3 + 0], y = xyz2[t * 3 + 1], z = xyz2[t * 3 + 2];
    cand[t] = make_float4(-2.f * x, -2.f * y, -2.f * z, x * x + y * y + z * z);
  } else if (t < NC + NW1) {
    int i = t - NC; int k = i >> 7, c = i & 127;
    w1t[c * 192 + k] = f2bf(W1[i]);
  } else if (t < NC + NW1 + NW2) {
    int i = t - NC - NW1; int k = i >> 7, c = i & 127;
    w2t[c * 128 + k] = f2bf(W2[i]);
  }
}

// ---- fused: three_nn + interp + concat + MLP(192->128->128) ----
__global__ __launch_bounds__(512, 8) void fused_kernel(
    const float* __restrict__ xyz1, const float* __restrict__ points1,
    const float* __restrict__ points2, const float4* __restrict__ cand,
    const unsigned short* __restrict__ w1t, const unsigned short* __restrict__ w2t,
    const float* __restrict__ bb1, const float* __restrict__ bb2,
    float* __restrict__ out) {

  // union: Ptop (phase1-2) -> Ash (phase3-4) -> Hsh (phase4-5); 25600 B total
  __shared__ __align__(16) unsigned char Ubuf[BQ * 200 * 2];
  unsigned short (*Ash)[200]  = (unsigned short (*)[200])Ubuf;
  uint2 (*Ptop)[BQ][3]        = (uint2 (*)[BQ][3])Ubuf;   // [8][64][3] = 12288 B
  unsigned short (*Hsh)[136]  = (unsigned short (*)[136])Ubuf;
  __shared__ float sW[BQ][3];
  __shared__ int   sJ[BQ][3];

  const int tid  = threadIdx.x;
  const int lane = tid & 63;
  const int wv   = __builtin_amdgcn_readfirstlane(tid >> 6);
  const int bid  = blockIdx.x;
  const int bb   = bid >> 8;            // 256 blocks per batch
  const int n0   = (bid & 255) * BQ;

  // ---------- phase 1: per-wave exact top-3 over its candidate chunk ----------
  const int q = n0 + lane;
  const float* xp = xyz1 + ((size_t)bb * N1_ + q) * 3;
  const float x = xp[0], y = xp[1], z = xp[2];
  const float q1 = fmaf(x, x, fmaf(y, y, z * z));
  const float4* cb = cand + (size_t)bb * N2_;
  const int jbase = wv * CHUNK;

  // 4 independent top-3 streams of (d_bits, idx) pairs
  unsigned d0[4], d1[4], d2[4], i0[4], i1[4], i2[4];
  #pragma unroll
  for (int s = 0; s < 4; ++s) {
    d0[s] = 0xFFFFFFFFu; d1[s] = 0xFFFFFFFFu; d2[s] = 0xFFFFFFFFu;
    i0[s] = 0u; i1[s] = 0u; i2[s] = 0u;
  }

  for (int j = 0; j < CHUNK; j += 16) {
    float4 cp[16];
    #pragma unroll
    for (int u = 0; u < 16; ++u) cp[u] = cb[jbase + j + u];
    #pragma unroll
    for (int u = 0; u < 16; ++u) {
      const int s = u & 3;
      // d = |q|^2 - 2 q.c + |c|^2  (cand pre-scaled by -2)
      const float d = fmaf(cp[u].x, x, fmaf(cp[u].y, y, fmaf(cp[u].z, z, q1 + cp[u].w)));
      const unsigned db = __builtin_bit_cast(unsigned, d);
      const unsigned jj = (unsigned)(jbase + j + u);
      INS3P(db, jj, d0[s], i0[s], d1[s], i1[s], d2[s], i2[s]);
    }
  }
  // merge 4 streams -> stream 0
  #pragma unroll
  for (int s = 1; s < 4; ++s) {
    INS3P(d0[s], i0[s], d0[0], i0[0], d1[0], i1[0], d2[0], i2[0]);
    INS3P(d1[s], i1[s], d0[0], i0[0], d1[0], i1[0], d2[0], i2[0]);
    INS3P(d2[s], i2[s], d0[0], i0[0], d1[0], i1[0], d2[0], i2[0]);
  }
  Ptop[wv][lane][0] = make_uint2(d0[0], i0[0]);
  Ptop[wv][lane][1] = make_uint2(d1[0], i1[0]);
  Ptop[wv][lane][2] = make_uint2(d2[0], i2[0]);
  __syncthreads();

  // ---------- phase 2: merge 8 waves' top-3 (wave order = idx order), weights ----------
  if (tid < BQ) {
    unsigned m0 = 0xFFFFFFFFu, m1 = 0xFFFFFFFFu, m2 = 0xFFFFFFFFu;
    unsigned n0i = 0u, n1i = 0u, n2i = 0u;
    #pragma unroll
    for (int w = 0; w < WV_; ++w)
      #pragma unroll
      for (int r = 0; r < 3; ++r) {
        const uint2 p = Ptop[w][tid][r];
        INS3P(p.x, p.y, m0, n0i, m1, n1i, m2, n2i);
      }
    const float dd0 = fmaxf(__builtin_bit_cast(float, m0), 1e-10f);
    const float dd1 = fmaxf(__builtin_bit_cast(float, m1), 1e-10f);
    const float dd2 = fmaxf(__builtin_bit_cast(float, m2), 1e-10f);
    const float r0 = 1.f / dd0, r1 = 1.f / dd1, r2 = 1.f / dd2;
    const float inorm = 1.f / (r0 + r1 + r2);
    sW[tid][0] = r0 * inorm; sW[tid][1] = r1 * inorm; sW[tid][2] = r2 * inorm;
    sJ[tid][0] = (int)n0i; sJ[tid][1] = (int)n1i; sJ[tid][2] = (int)n2i;
  }
  __syncthreads();

  // ---------- phase 3: gather + interpolate + concat into bf16 A tile ----------
  {
    const int qq = tid >> 3, cq = tid & 7;    // 8 threads per query
    const float w0 = sW[qq][0], w1 = sW[qq][1], w2 = sW[qq][2];
    const float* f0 = points2 + ((size_t)bb * N2_ + sJ[qq][0]) * C2_;
    const float* f1 = points2 + ((size_t)bb * N2_ + sJ[qq][1]) * C2_;
    const float* f2 = points2 + ((size_t)bb * N2_ + sJ[qq][2]) * C2_;
    #pragma unroll
    for (int c = cq * 16; c < cq * 16 + 16; c += 4) {
      const float4 a  = *(const float4*)(f0 + c);
      const float4 bv = *(const float4*)(f1 + c);
      const float4 cv = *(const float4*)(f2 + c);
      u16x4 pk;
      pk.x = f2bf(fmaf(w2, cv.x, fmaf(w1, bv.x, w0 * a.x)));
      pk.y = f2bf(fmaf(w2, cv.y, fmaf(w1, bv.y, w0 * a.y)));
      pk.z = f2bf(fmaf(w2, cv.z, fmaf(w1, bv.z, w0 * a.z)));
      pk.w = f2bf(fmaf(w2, cv.w, fmaf(w1, bv.w, w0 * a.w)));
      *(u16x4*)&Ash[qq][c] = pk;
    }
    const float* p1 = points1 + ((size_t)bb * N1_ + n0 + qq) * C1_;
    #pragma unroll
    for (int c = cq * 8; c < cq * 8 + 8; c += 4) {
      const float4 v = *(const float4*)(p1 + c);
      u16x4 pk;
      pk.x = f2bf(v.x); pk.y = f2bf(v.y); pk.z = f2bf(v.z); pk.w = f2bf(v.w);
      *(u16x4*)&Ash[qq][128 + c] = pk;
    }
  }
  __syncthreads();

  // ---------- phase 4: GEMM1  (64x192) x (192x128), wave = 16-col slice ----------
  const int lr = lane & 15;
  const int lg = lane >> 4;
  const int c0 = wv * 16;
  const int col = c0 + lr;
  f32x4 acc[4];
  #pragma unroll
  for (int m = 0; m < 4; ++m) acc[m] = (f32x4){0.f, 0.f, 0.f, 0.f};

  #pragma unroll
  for (int kk = 0; kk < 6; ++kk) {
    const int kof = kk * 32 + lg * 8;
    const bf16x8 bfr = *(const bf16x8*)(w1t + (size_t)col * 192 + kof);
    #pragma unroll
    for (int m = 0; m < 4; ++m) {
      const bf16x8 af = *(const bf16x8*)&Ash[m * 16 + lr][kof];
      acc[m] = __builtin_amdgcn_mfma_f32_16x16x32_bf16(af, bfr, acc[m], 0, 0, 0);
    }
  }
  __syncthreads();   // all waves done READING Ash before H overwrites the union

  {
    const float bias = bb1[col];
    #pragma unroll
    for (int m = 0; m < 4; ++m)
      #pragma unroll
      for (int e = 0; e < 4; ++e) {
        const int row = m * 16 + lg * 4 + e;
        Hsh[row][col] = f2bf(fmaxf(acc[m][e] + bias, 0.f));
      }
  }
  __syncthreads();

  // ---------- phase 5: GEMM2  (64x128) x (128x128), relu, store f32 ----------
  f32x4 acc2[4];
  #pragma unroll
  for (int m = 0; m < 4; ++m) acc2[m] = (f32x4){0.f, 0.f, 0.f, 0.f};

  #pragma unroll
  for (int kk = 0; kk < 4; ++kk) {
    const int kof = kk * 32 + lg * 8;
    const bf16x8 bfr = *(const bf16x8*)(w2t + (size_t)col * 128 + kof);
    #pragma unroll
    for (int m = 0; m < 4; ++m) {
      const bf16x8 af = *(const bf16x8*)&Hsh[m * 16 + lr][kof];
      acc2[m] = __builtin_amdgcn_mfma_f32_16x16x32_bf16(af, bfr, acc2[m], 0, 0, 0);
    }
  }
  {
    const float bias = bb2[col];
    #pragma unroll
    for (int m = 0; m < 4; ++m)
      #pragma unroll
      for (int e = 0; e < 4; ++e) {
        const int row = m * 16 + lg * 4 + e;
        out[((size_t)bb * N1_ + n0 + row) * 128 + col] = fmaxf(acc2[m][e] + bias, 0.f);
      }
  }
}

extern "C" void kernel_launch(void* const* d_in, const int* in_sizes, int n_in,
                              void* d_out, int out_size, void* d_ws, size_t ws_size,
                              hipStream_t stream) {
  const float* xyz1    = (const float*)d_in[0];
  const float* xyz2    = (const float*)d_in[1];
  const float* points1 = (const float*)d_in[2];
  const float* points2 = (const float*)d_in[3];
  const float* W1      = (const float*)d_in[4];
  const float* b1      = (const float*)d_in[5];
  const float* W2      = (const float*)d_in[6];
  const float* b2      = (const float*)d_in[7];
  float* out = (float*)d_out;

  char* ws = (char*)d_ws;
  float4*         cand = (float4*)ws;                        // 4*4096*16   = 262144 B
  unsigned short* w1t  = (unsigned short*)(ws + 262144);     // 192*128*2   =  49152 B
  unsigned short* w2t  = (unsigned short*)(ws + 311296);     // 128*128*2   =  32768 B

  prep_kernel<<<224, 256, 0, stream>>>(xyz2, W1, W2, cand, w1t, w2t);
  fused_kernel<<<1024, 512, 0, stream>>>(xyz1, points1, points2, cand, w1t, w2t, b1, b2, out);
}

// Round 6
// 119.013 us; speedup vs baseline: 1.1888x; 1.1888x over previous
//
#include <hip/hip_runtime.h>

#define B_    4
#define N1_   16384
#define N2_   4096
#define C1_   64
#define C2_   128
#define BQ    64            // queries per block
#define WV_   8             // waves per block
#define CHUNK (N2_ / WV_)   // candidates per wave in phase 1 = 512

typedef __attribute__((ext_vector_type(8))) short bf16x8;
typedef __attribute__((ext_vector_type(4))) float f32x4;
typedef __attribute__((ext_vector_type(4))) unsigned short u16x4;

__device__ __forceinline__ unsigned short f2bf(float f) {
  unsigned int u = __builtin_bit_cast(unsigned int, f);
  unsigned int r = (u + 0x7FFFu + ((u >> 16) & 1u)) >> 16;
  return (unsigned short)r;
}
__device__ __forceinline__ unsigned umn(unsigned a, unsigned b) { return a < b ? a : b; }
__device__ __forceinline__ unsigned umx(unsigned a, unsigned b) { return a > b ? a : b; }

// value-only insert: keep 3 smallest u32, 5 full-rate ops (v_min_u32/v_max_u32)
#define INS3U(x, m0, m1, m2) do {           \
    unsigned _a = umx((x), (m0));           \
    (m0) = umn((x), (m0));                  \
    unsigned _b = umx(_a, (m1));            \
    (m1) = umn(_a, (m1));                   \
    (m2) = umn(_b, (m2));                   \
  } while (0)

// exact insert of 64-bit lexicographic key (d_bits<<32 | idx) via f64 min/max
#define INS3D(x, m0, m1, m2) do {           \
    double _a = fmax((x), (m0));            \
    (m0) = fmin((x), (m0));                 \
    double _b = fmax(_a, (m1));             \
    (m1) = fmin(_a, (m1));                  \
    (m2) = fmin(_b, (m2));                  \
  } while (0)

#define KINF __builtin_bit_cast(double, 0x7FF0000000000000ULL)

// ---- prep: pack candidates (-2x,-2y,-2z,|c|^2), transpose W1/W2 to bf16 ----
__global__ void prep_kernel(const float* __restrict__ xyz2, const float* __restrict__ W1,
                            const float* __restrict__ W2,
                            float4* __restrict__ cand, unsigned short* __restrict__ w1t,
                            unsigned short* __restrict__ w2t) {
  int t = blockIdx.x * 256 + threadIdx.x;
  const int NC  = B_ * N2_;     // 16384
  const int NW1 = 192 * 128;    // 24576
  const int NW2 = 128 * 128;    // 16384
  if (t < NC) {
    float x = xyz2[t * 3 + 0], y = xyz2[t * 3 + 1], z = xyz2[t * 3 + 2];
    cand[t] = make_float4(-2.f * x, -2.f * y, -2.f * z, x * x + y * y + z * z);
  } else if (t < NC + NW1) {
    int i = t - NC; int k = i >> 7, c = i & 127;
    w1t[c * 192 + k] = f2bf(W1[i]);
  } else if (t < NC + NW1 + NW2) {
    int i = t - NC - NW1; int k = i >> 7, c = i & 127;
    w2t[c * 128 + k] = f2bf(W2[i]);
  }
}

// ---- fused: three_nn + interp + concat + MLP(192->128->128) ----
__global__ __launch_bounds__(512, 8) void fused_kernel(
    const float* __restrict__ xyz1, const float* __restrict__ points1,
    const float* __restrict__ points2, const float4* __restrict__ cand,
    const unsigned short* __restrict__ w1t, const unsigned short* __restrict__ w2t,
    const float* __restrict__ bb1, const float* __restrict__ bb2,
    float* __restrict__ out) {

  // union: PtopU/Ptop (phase1-2) -> Ash (phase3-4) -> Hsh (phase4-5); 25600 B
  __shared__ __align__(16) unsigned char Ubuf[BQ * 200 * 2];
  unsigned short (*Ash)[200]  = (unsigned short (*)[200])Ubuf;
  unsigned (*PtopU)[BQ][3]    = (unsigned (*)[BQ][3])Ubuf;   // [8][64][3] u32 = 6144 B
  double (*Ptop)[BQ][3]       = (double (*)[BQ][3])Ubuf;     // [8][64][3] f64 = 12288 B
  unsigned short (*Hsh)[136]  = (unsigned short (*)[136])Ubuf;
  __shared__ float sW[BQ][3];
  __shared__ int   sJ[BQ][3];
  __shared__ unsigned sM2[BQ];

  const int tid  = threadIdx.x;
  const int lane = tid & 63;
  const int wv   = __builtin_amdgcn_readfirstlane(tid >> 6);
  const int bid  = blockIdx.x;
  const int bb   = bid >> 8;            // 256 blocks per batch
  const int n0   = (bid & 255) * BQ;

  const int q = n0 + lane;
  const float* xp = xyz1 + ((size_t)bb * N1_ + q) * 3;
  const float x = xp[0], y = xp[1], z = xp[2];
  const float q1 = fmaf(x, x, fmaf(y, y, z * z));
  const float4* cb = cand + (size_t)bb * N2_;
  const int jbase = wv * CHUNK;

  // ---------- pass 1: per-wave top-3 VALUES only (u32 min/max network) ----------
  unsigned a0[4], a1[4], a2[4];
  #pragma unroll
  for (int s = 0; s < 4; ++s) { a0[s] = 0xFFFFFFFFu; a1[s] = 0xFFFFFFFFu; a2[s] = 0xFFFFFFFFu; }

  for (int j = 0; j < CHUNK; j += 16) {
    float4 cp[16];
    #pragma unroll
    for (int u = 0; u < 16; ++u) cp[u] = cb[jbase + j + u];
    #pragma unroll
    for (int u = 0; u < 16; ++u) {
      const int s = u & 3;
      // d = |q|^2 - 2 q.c + |c|^2  (cand pre-scaled by -2)
      const float d = fmaf(cp[u].x, x, fmaf(cp[u].y, y, fmaf(cp[u].z, z, q1 + cp[u].w)));
      const unsigned db = __builtin_bit_cast(unsigned, d);
      INS3U(db, a0[s], a1[s], a2[s]);
    }
  }
  #pragma unroll
  for (int s = 1; s < 4; ++s) {
    INS3U(a0[s], a0[0], a1[0], a2[0]);
    INS3U(a1[s], a0[0], a1[0], a2[0]);
    INS3U(a2[s], a0[0], a1[0], a2[0]);
  }
  PtopU[wv][lane][0] = a0[0]; PtopU[wv][lane][1] = a1[0]; PtopU[wv][lane][2] = a2[0];
  __syncthreads();

  // ---------- phase 2a: merge 8 chunk value-triples -> global 3rd-smallest ----------
  if (tid < BQ) {
    unsigned m0 = 0xFFFFFFFFu, m1 = 0xFFFFFFFFu, m2v = 0xFFFFFFFFu;
    #pragma unroll
    for (int w = 0; w < WV_; ++w)
      #pragma unroll
      for (int r = 0; r < 3; ++r)
        INS3U(PtopU[w][tid][r], m0, m1, m2v);
    sM2[tid] = m2v;
  }
  __syncthreads();

  // ---------- pass 2: rescan, capture candidates with db <= m2 (rare) exactly ----------
  const unsigned m2t = sM2[lane];
  double k0 = KINF, k1 = KINF, k2 = KINF;
  for (int j = 0; j < CHUNK; j += 16) {
    float4 cp[16];
    #pragma unroll
    for (int u = 0; u < 16; ++u) cp[u] = cb[jbase + j + u];
    #pragma unroll
    for (int g = 0; g < 4; ++g) {
      unsigned db[4];
      #pragma unroll
      for (int u = 0; u < 4; ++u) {
        const int uu = g * 4 + u;
        const float d = fmaf(cp[uu].x, x, fmaf(cp[uu].y, y, fmaf(cp[uu].z, z, q1 + cp[uu].w)));
        db[u] = __builtin_bit_cast(unsigned, d);
      }
      const unsigned gm = umn(umn(db[0], db[1]), umn(db[2], db[3]));
      if (gm <= m2t) {                       // execz-skipped ~83% of groups
        #pragma unroll
        for (int u = 0; u < 4; ++u) {
          if (db[u] <= m2t) {                // execz-skipped ~95%
            const unsigned long long kk =
                ((unsigned long long)db[u] << 32) | (unsigned)(jbase + j + g * 4 + u);
            const double xk = __builtin_bit_cast(double, kk);
            INS3D(xk, k0, k1, k2);
          }
        }
      }
    }
  }
  Ptop[wv][lane][0] = k0; Ptop[wv][lane][1] = k1; Ptop[wv][lane][2] = k2;
  __syncthreads();

  // ---------- phase 2b: merge captured exact keys, compute weights ----------
  if (tid < BQ) {
    double m0 = KINF, m1 = KINF, m2 = KINF;
    #pragma unroll
    for (int w = 0; w < WV_; ++w)
      #pragma unroll
      for (int r = 0; r < 3; ++r) {
        const double xk = Ptop[w][tid][r];
        INS3D(xk, m0, m1, m2);
      }
    const unsigned long long u0 = __builtin_bit_cast(unsigned long long, m0);
    const unsigned long long u1 = __builtin_bit_cast(unsigned long long, m1);
    const unsigned long long u2 = __builtin_bit_cast(unsigned long long, m2);
    const float d0 = fmaxf(__builtin_bit_cast(float, (unsigned)(u0 >> 32)), 1e-10f);
    const float d1 = fmaxf(__builtin_bit_cast(float, (unsigned)(u1 >> 32)), 1e-10f);
    const float d2 = fmaxf(__builtin_bit_cast(float, (unsigned)(u2 >> 32)), 1e-10f);
    const float r0 = 1.f / d0, r1 = 1.f / d1, r2 = 1.f / d2;
    const float inorm = 1.f / (r0 + r1 + r2);
    sW[tid][0] = r0 * inorm; sW[tid][1] = r1 * inorm; sW[tid][2] = r2 * inorm;
    sJ[tid][0] = (int)(unsigned)u0; sJ[tid][1] = (int)(unsigned)u1; sJ[tid][2] = (int)(unsigned)u2;
  }
  __syncthreads();

  // ---------- phase 3: gather + interpolate + concat into bf16 A tile ----------
  {
    const int qq = tid >> 3, cq = tid & 7;    // 8 threads per query
    const float w0 = sW[qq][0], w1 = sW[qq][1], w2 = sW[qq][2];
    const float* f0 = points2 + ((size_t)bb * N2_ + sJ[qq][0]) * C2_;
    const float* f1 = points2 + ((size_t)bb * N2_ + sJ[qq][1]) * C2_;
    const float* f2 = points2 + ((size_t)bb * N2_ + sJ[qq][2]) * C2_;
    #pragma unroll
    for (int c = cq * 16; c < cq * 16 + 16; c += 4) {
      const float4 a  = *(const float4*)(f0 + c);
      const float4 bv = *(const float4*)(f1 + c);
      const float4 cv = *(const float4*)(f2 + c);
      u16x4 pk;
      pk.x = f2bf(fmaf(w2, cv.x, fmaf(w1, bv.x, w0 * a.x)));
      pk.y = f2bf(fmaf(w2, cv.y, fmaf(w1, bv.y, w0 * a.y)));
      pk.z = f2bf(fmaf(w2, cv.z, fmaf(w1, bv.z, w0 * a.z)));
      pk.w = f2bf(fmaf(w2, cv.w, fmaf(w1, bv.w, w0 * a.w)));
      *(u16x4*)&Ash[qq][c] = pk;
    }
    const float* p1 = points1 + ((size_t)bb * N1_ + n0 + qq) * C1_;
    #pragma unroll
    for (int c = cq * 8; c < cq * 8 + 8; c += 4) {
      const float4 v = *(const float4*)(p1 + c);
      u16x4 pk;
      pk.x = f2bf(v.x); pk.y = f2bf(v.y); pk.z = f2bf(v.z); pk.w = f2bf(v.w);
      *(u16x4*)&Ash[qq][128 + c] = pk;
    }
  }
  __syncthreads();

  // ---------- phase 4: GEMM1  (64x192) x (192x128), wave = 16-col slice ----------
  const int lr = lane & 15;
  const int lg = lane >> 4;
  const int c0 = wv * 16;
  const int col = c0 + lr;
  f32x4 acc[4];
  #pragma unroll
  for (int m = 0; m < 4; ++m) acc[m] = (f32x4){0.f, 0.f, 0.f, 0.f};

  #pragma unroll
  for (int kk = 0; kk < 6; ++kk) {
    const int kof = kk * 32 + lg * 8;
    const bf16x8 bfr = *(const bf16x8*)(w1t + (size_t)col * 192 + kof);
    #pragma unroll
    for (int m = 0; m < 4; ++m) {
      const bf16x8 af = *(const bf16x8*)&Ash[m * 16 + lr][kof];
      acc[m] = __builtin_amdgcn_mfma_f32_16x16x32_bf16(af, bfr, acc[m], 0, 0, 0);
    }
  }
  __syncthreads();   // all waves done READING Ash before H overwrites the union

  {
    const float bias = bb1[col];
    #pragma unroll
    for (int m = 0; m < 4; ++m)
      #pragma unroll
      for (int e = 0; e < 4; ++e) {
        const int row = m * 16 + lg * 4 + e;
        Hsh[row][col] = f2bf(fmaxf(acc[m][e] + bias, 0.f));
      }
  }
  __syncthreads();

  // ---------- phase 5: GEMM2  (64x128) x (128x128), relu, store f32 ----------
  f32x4 acc2[4];
  #pragma unroll
  for (int m = 0; m < 4; ++m) acc2[m] = (f32x4){0.f, 0.f, 0.f, 0.f};

  #pragma unroll
  for (int kk = 0; kk < 4; ++kk) {
    const int kof = kk * 32 + lg * 8;
    const bf16x8 bfr = *(const bf16x8*)(w2t + (size_t)col * 128 + kof);
    #pragma unroll
    for (int m = 0; m < 4; ++m) {
      const bf16x8 af = *(const bf16x8*)&Hsh[m * 16 + lr][kof];
      acc2[m] = __builtin_amdgcn_mfma_f32_16x16x32_bf16(af, bfr, acc2[m], 0, 0, 0);
    }
  }
  {
    const float bias = bb2[col];
    #pragma unroll
    for (int m = 0; m < 4; ++m)
      #pragma unroll
      for (int e = 0; e < 4; ++e) {
        const int row = m * 16 + lg * 4 + e;
        out[((size_t)bb * N1_ + n0 + row) * 128 + col] = fmaxf(acc2[m][e] + bias, 0.f);
      }
  }
}

extern "C" void kernel_launch(void* const* d_in, const int* in_sizes, int n_in,
                              void* d_out, int out_size, void* d_ws, size_t ws_size,
                              hipStream_t stream) {
  const float* xyz1    = (const float*)d_in[0];
  const float* xyz2    = (const float*)d_in[1];
  const float* points1 = (const float*)d_in[2];
  const float* points2 = (const float*)d_in[3];
  const float* W1      = (const float*)d_in[4];
  const float* b1      = (const float*)d_in[5];
  const float* W2      = (const float*)d_in[6];
  const float* b2      = (const float*)d_in[7];
  float* out = (float*)d_out;

  char* ws = (char*)d_ws;
  float4*         cand = (float4*)ws;                        // 4*4096*16   = 262144 B
  unsigned short* w1t  = (unsigned short*)(ws + 262144);     // 192*128*2   =  49152 B
  unsigned short* w2t  = (unsigned short*)(ws + 311296);     // 128*128*2   =  32768 B

  prep_kernel<<<224, 256, 0, stream>>>(xyz2, W1, W2, cand, w1t, w2t);
  fused_kernel<<<1024, 512, 0, stream>>>(xyz1, points1, points2, cand, w1t, w2t, b1, b2, out);
}

// Round 7
// 107.732 us; speedup vs baseline: 1.3133x; 1.1047x over previous
//
#include <hip/hip_runtime.h>

#define B_    4
#define N1_   16384
#define N2_   4096
#define C1_   64
#define C2_   128
#define BQ    64            // queries per block
#define WV_   8             // waves per block
#define CHUNK (N2_ / WV_)   // candidates per wave in phase 1 = 512

typedef __attribute__((ext_vector_type(8))) short bf16x8;
typedef __attribute__((ext_vector_type(4))) float f32x4;
typedef __attribute__((ext_vector_type(4))) unsigned short u16x4;

__device__ __forceinline__ unsigned short f2bf(float f) {
  unsigned int u = __builtin_bit_cast(unsigned int, f);
  unsigned int r = (u + 0x7FFFu + ((u >> 16) & 1u)) >> 16;
  return (unsigned short)r;
}
__device__ __forceinline__ unsigned umn(unsigned a, unsigned b) { return a < b ? a : b; }
__device__ __forceinline__ unsigned umx(unsigned a, unsigned b) { return a > b ? a : b; }

// value-only insert: keep 3 smallest u32, 5 full-rate ops (v_min_u32/v_max_u32)
#define INS3U(x, m0, m1, m2) do {           \
    unsigned _a = umx((x), (m0));           \
    (m0) = umn((x), (m0));                  \
    unsigned _b = umx(_a, (m1));            \
    (m1) = umn(_a, (m1));                   \
    (m2) = umn(_b, (m2));                   \
  } while (0)

// (d,idx) pair insert, keep 3 smallest by (d, arrival order); arrivals come in
// ascending idx -> lexicographic (d, idx) with lower-idx-wins. Proven in R5.
#define INS3P(db, jj, d0, i0, d1, i1, d2, i2) do {          \
    const bool _c0 = (db) < (d0);                            \
    const unsigned _ad = _c0 ? (d0) : (db);                  \
    const unsigned _ai = _c0 ? (i0) : (jj);                  \
    (i0) = _c0 ? (jj) : (i0);                                \
    (d0) = _c0 ? (db) : (d0);                                \
    const bool _c1 = _ad < (d1);                             \
    const unsigned _bd = _c1 ? (d1) : _ad;                   \
    const unsigned _bi = _c1 ? (i1) : _ai;                   \
    (i1) = _c1 ? _ai : (i1);                                 \
    (d1) = _c1 ? _ad : (d1);                                 \
    const bool _c2 = _bd < (d2);                             \
    (i2) = _c2 ? _bi : (i2);                                 \
    (d2) = _c2 ? _bd : (d2);                                 \
  } while (0)

// ---- prep: pack candidates (-2x,-2y,-2z,|c|^2), transpose W1/W2 to bf16 ----
__global__ void prep_kernel(const float* __restrict__ xyz2, const float* __restrict__ W1,
                            const float* __restrict__ W2,
                            float4* __restrict__ cand, unsigned short* __restrict__ w1t,
                            unsigned short* __restrict__ w2t) {
  int t = blockIdx.x * 256 + threadIdx.x;
  const int NC  = B_ * N2_;     // 16384
  const int NW1 = 192 * 128;    // 24576
  const int NW2 = 128 * 128;    // 16384
  if (t < NC) {
    float x = xyz2[t * 3 + 0], y = xyz2[t * 3 + 1], z = xyz2[t * 3 + 2];
    cand[t] = make_float4(-2.f * x, -2.f * y, -2.f * z, x * x + y * y + z * z);
  } else if (t < NC + NW1) {
    int i = t - NC; int k = i >> 7, c = i & 127;
    w1t[c * 192 + k] = f2bf(W1[i]);
  } else if (t < NC + NW1 + NW2) {
    int i = t - NC - NW1; int k = i >> 7, c = i & 127;
    w2t[c * 128 + k] = f2bf(W2[i]);
  }
}

// ---- fused: three_nn + interp + concat + MLP(192->128->128) ----
__global__ __launch_bounds__(512, 8) void fused_kernel(
    const float* __restrict__ xyz1, const float* __restrict__ points1,
    const float* __restrict__ points2, const float4* __restrict__ cand,
    const unsigned short* __restrict__ w1t, const unsigned short* __restrict__ w2t,
    const float* __restrict__ bb1, const float* __restrict__ bb2,
    float* __restrict__ out) {

  // union: PtopU/PtopP (phase1-2) -> Ash (phase3-4) -> Hsh (phase4-5); 25600 B
  __shared__ __align__(16) unsigned char Ubuf[BQ * 200 * 2];
  unsigned short (*Ash)[200]  = (unsigned short (*)[200])Ubuf;
  unsigned (*PtopU)[BQ][3]    = (unsigned (*)[BQ][3])Ubuf;   // [8][64][3] u32  =  6144 B
  uint2 (*PtopP)[BQ][3]       = (uint2 (*)[BQ][3])Ubuf;      // [8][64][3] uint2 = 12288 B
  unsigned short (*Hsh)[136]  = (unsigned short (*)[136])Ubuf;
  __shared__ float sW[BQ][3];
  __shared__ int   sJ[BQ][3];
  __shared__ unsigned sM2[BQ];

  const int tid  = threadIdx.x;
  const int lane = tid & 63;
  const int wv   = __builtin_amdgcn_readfirstlane(tid >> 6);
  const int bid  = blockIdx.x;
  const int bb   = bid >> 8;            // 256 blocks per batch
  const int n0   = (bid & 255) * BQ;

  const int q = n0 + lane;
  const float* xp = xyz1 + ((size_t)bb * N1_ + q) * 3;
  const float x = xp[0], y = xp[1], z = xp[2];
  const float q1 = fmaf(x, x, fmaf(y, y, z * z));
  const float4* cb = cand + (size_t)bb * N2_;
  const int jbase = wv * CHUNK;

  // ---------- pass 1: per-wave 3 smallest QUAD-MINS (upper bound on v3) ----------
  unsigned m0 = 0xFFFFFFFFu, m1 = 0xFFFFFFFFu, m2 = 0xFFFFFFFFu;
  for (int j = 0; j < CHUNK; j += 16) {
    float4 cp[16];
    #pragma unroll
    for (int u = 0; u < 16; ++u) cp[u] = cb[jbase + j + u];
    #pragma unroll
    for (int g = 0; g < 4; ++g) {
      unsigned db[4];
      #pragma unroll
      for (int u = 0; u < 4; ++u) {
        const int uu = g * 4 + u;
        const float d = fmaf(cp[uu].x, x, fmaf(cp[uu].y, y, fmaf(cp[uu].z, z, q1 + cp[uu].w)));
        db[u] = __builtin_bit_cast(unsigned, d);
      }
      const unsigned gm = umn(umn(umn(db[0], db[1]), db[2]), db[3]);
      INS3U(gm, m0, m1, m2);
    }
  }
  PtopU[wv][lane][0] = m0; PtopU[wv][lane][1] = m1; PtopU[wv][lane][2] = m2;
  __syncthreads();

  // ---------- phase 2a: merge 8 waves' quad-min triples -> threshold >= v3 ----------
  if (tid < BQ) {
    unsigned t0 = 0xFFFFFFFFu, t1 = 0xFFFFFFFFu, t2 = 0xFFFFFFFFu;
    #pragma unroll
    for (int w = 0; w < WV_; ++w)
      #pragma unroll
      for (int r = 0; r < 3; ++r)
        INS3U(PtopU[w][tid][r], t0, t1, t2);
    sM2[tid] = t2;
  }
  __syncthreads();

  // ---------- pass 2: rescan, capture (d,idx) with d <= threshold (rare) ----------
  const unsigned m2t = sM2[lane];
  unsigned cd0 = 0xFFFFFFFFu, cd1 = 0xFFFFFFFFu, cd2 = 0xFFFFFFFFu;
  unsigned ci0 = 0u, ci1 = 0u, ci2 = 0u;
  for (int j = 0; j < CHUNK; j += 16) {
    float4 cp[16];
    #pragma unroll
    for (int u = 0; u < 16; ++u) cp[u] = cb[jbase + j + u];
    #pragma unroll
    for (int g = 0; g < 4; ++g) {
      unsigned db[4];
      #pragma unroll
      for (int u = 0; u < 4; ++u) {
        const int uu = g * 4 + u;
        const float d = fmaf(cp[uu].x, x, fmaf(cp[uu].y, y, fmaf(cp[uu].z, z, q1 + cp[uu].w)));
        db[u] = __builtin_bit_cast(unsigned, d);
      }
      const unsigned gm = umn(umn(umn(db[0], db[1]), db[2]), db[3]);
      if (gm <= m2t) {
        #pragma unroll
        for (int u = 0; u < 4; ++u) {
          if (db[u] <= m2t) {
            const unsigned jj = (unsigned)(jbase + j + g * 4 + u);
            INS3P(db[u], jj, cd0, ci0, cd1, ci1, cd2, ci2);
          }
        }
      }
    }
  }
  PtopP[wv][lane][0] = make_uint2(cd0, ci0);
  PtopP[wv][lane][1] = make_uint2(cd1, ci1);
  PtopP[wv][lane][2] = make_uint2(cd2, ci2);
  __syncthreads();

  // ---------- phase 2b: merge captured pairs (wave order = idx order), weights ----------
  if (tid < BQ) {
    unsigned g0 = 0xFFFFFFFFu, g1 = 0xFFFFFFFFu, g2 = 0xFFFFFFFFu;
    unsigned h0 = 0u, h1 = 0u, h2 = 0u;
    #pragma unroll
    for (int w = 0; w < WV_; ++w)
      #pragma unroll
      for (int r = 0; r < 3; ++r) {
        const uint2 p = PtopP[w][tid][r];
        INS3P(p.x, p.y, g0, h0, g1, h1, g2, h2);
      }
    const float dd0 = fmaxf(__builtin_bit_cast(float, g0), 1e-10f);
    const float dd1 = fmaxf(__builtin_bit_cast(float, g1), 1e-10f);
    const float dd2 = fmaxf(__builtin_bit_cast(float, g2), 1e-10f);
    const float r0 = 1.f / dd0, r1 = 1.f / dd1, r2 = 1.f / dd2;
    const float inorm = 1.f / (r0 + r1 + r2);
    sW[tid][0] = r0 * inorm; sW[tid][1] = r1 * inorm; sW[tid][2] = r2 * inorm;
    sJ[tid][0] = (int)h0; sJ[tid][1] = (int)h1; sJ[tid][2] = (int)h2;
  }
  __syncthreads();

  // ---------- phase 3: gather + interpolate + concat into bf16 A tile ----------
  {
    const int qq = tid >> 3, cq = tid & 7;    // 8 threads per query
    const float w0 = sW[qq][0], w1 = sW[qq][1], w2 = sW[qq][2];
    const float* f0 = points2 + ((size_t)bb * N2_ + sJ[qq][0]) * C2_;
    const float* f1 = points2 + ((size_t)bb * N2_ + sJ[qq][1]) * C2_;
    const float* f2 = points2 + ((size_t)bb * N2_ + sJ[qq][2]) * C2_;
    #pragma unroll
    for (int c = cq * 16; c < cq * 16 + 16; c += 4) {
      const float4 a  = *(const float4*)(f0 + c);
      const float4 bv = *(const float4*)(f1 + c);
      const float4 cv = *(const float4*)(f2 + c);
      u16x4 pk;
      pk.x = f2bf(fmaf(w2, cv.x, fmaf(w1, bv.x, w0 * a.x)));
      pk.y = f2bf(fmaf(w2, cv.y, fmaf(w1, bv.y, w0 * a.y)));
      pk.z = f2bf(fmaf(w2, cv.z, fmaf(w1, bv.z, w0 * a.z)));
      pk.w = f2bf(fmaf(w2, cv.w, fmaf(w1, bv.w, w0 * a.w)));
      *(u16x4*)&Ash[qq][c] = pk;
    }
    const float* p1 = points1 + ((size_t)bb * N1_ + n0 + qq) * C1_;
    #pragma unroll
    for (int c = cq * 8; c < cq * 8 + 8; c += 4) {
      const float4 v = *(const float4*)(p1 + c);
      u16x4 pk;
      pk.x = f2bf(v.x); pk.y = f2bf(v.y); pk.z = f2bf(v.z); pk.w = f2bf(v.w);
      *(u16x4*)&Ash[qq][128 + c] = pk;
    }
  }
  __syncthreads();

  // ---------- phase 4: GEMM1  (64x192) x (192x128), wave = 16-col slice ----------
  const int lr = lane & 15;
  const int lg = lane >> 4;
  const int c0 = wv * 16;
  const int col = c0 + lr;
  f32x4 acc[4];
  #pragma unroll
  for (int m = 0; m < 4; ++m) acc[m] = (f32x4){0.f, 0.f, 0.f, 0.f};

  #pragma unroll
  for (int kk = 0; kk < 6; ++kk) {
    const int kof = kk * 32 + lg * 8;
    const bf16x8 bfr = *(const bf16x8*)(w1t + (size_t)col * 192 + kof);
    #pragma unroll
    for (int m = 0; m < 4; ++m) {
      const bf16x8 af = *(const bf16x8*)&Ash[m * 16 + lr][kof];
      acc[m] = __builtin_amdgcn_mfma_f32_16x16x32_bf16(af, bfr, acc[m], 0, 0, 0);
    }
  }
  __syncthreads();   // all waves done READING Ash before H overwrites the union

  {
    const float bias = bb1[col];
    #pragma unroll
    for (int m = 0; m < 4; ++m)
      #pragma unroll
      for (int e = 0; e < 4; ++e) {
        const int row = m * 16 + lg * 4 + e;
        Hsh[row][col] = f2bf(fmaxf(acc[m][e] + bias, 0.f));
      }
  }
  __syncthreads();

  // ---------- phase 5: GEMM2  (64x128) x (128x128), relu, store f32 ----------
  f32x4 acc2[4];
  #pragma unroll
  for (int m = 0; m < 4; ++m) acc2[m] = (f32x4){0.f, 0.f, 0.f, 0.f};

  #pragma unroll
  for (int kk = 0; kk < 4; ++kk) {
    const int kof = kk * 32 + lg * 8;
    const bf16x8 bfr = *(const bf16x8*)(w2t + (size_t)col * 128 + kof);
    #pragma unroll
    for (int m = 0; m < 4; ++m) {
      const bf16x8 af = *(const bf16x8*)&Hsh[m * 16 + lr][kof];
      acc2[m] = __builtin_amdgcn_mfma_f32_16x16x32_bf16(af, bfr, acc2[m], 0, 0, 0);
    }
  }
  {
    const float bias = bb2[col];
    #pragma unroll
    for (int m = 0; m < 4; ++m)
      #pragma unroll
      for (int e = 0; e < 4; ++e) {
        const int row = m * 16 + lg * 4 + e;
        out[((size_t)bb * N1_ + n0 + row) * 128 + col] = fmaxf(acc2[m][e] + bias, 0.f);
      }
  }
}

extern "C" void kernel_launch(void* const* d_in, const int* in_sizes, int n_in,
                              void* d_out, int out_size, void* d_ws, size_t ws_size,
                              hipStream_t stream) {
  const float* xyz1    = (const float*)d_in[0];
  const float* xyz2    = (const float*)d_in[1];
  const float* points1 = (const float*)d_in[2];
  const float* points2 = (const float*)d_in[3];
  const float* W1      = (const float*)d_in[4];
  const float* b1      = (const float*)d_in[5];
  const float* W2      = (const float*)d_in[6];
  const float* b2      = (const float*)d_in[7];
  float* out = (float*)d_out;

  char* ws = (char*)d_ws;
  float4*         cand = (float4*)ws;                        // 4*4096*16   = 262144 B
  unsigned short* w1t  = (unsigned short*)(ws + 262144);     // 192*128*2   =  49152 B
  unsigned short* w2t  = (unsigned short*)(ws + 311296);     // 128*128*2   =  32768 B

  prep_kernel<<<224, 256, 0, stream>>>(xyz2, W1, W2, cand, w1t, w2t);
  fused_kernel<<<1024, 512, 0, stream>>>(xyz1, points1, points2, cand, w1t, w2t, b1, b2, out);
}